// Round 13
// baseline (340.006 us; speedup 1.0000x reference)
//
#include <hip/hip_runtime.h>
#include <math.h>

#define BB 8
#define LL 1024
#define DD 768
#define NNs 16
#define RR 48

typedef __attribute__((ext_vector_type(8))) short bf16x8;
typedef __attribute__((ext_vector_type(4))) float f32x4;
typedef __attribute__((ext_vector_type(2))) float f32x2;

__device__ __forceinline__ float silu_f(float v) { return v / (1.0f + __expf(-v)); }

__device__ __forceinline__ short f2bf(float f) {
    union { float f; unsigned u; } v; v.f = f;
    unsigned r = (v.u + 0x7fffu + ((v.u >> 16) & 1u)) >> 16;
    return (short)r;
}

// raw v_exp_f32: computes 2^x (caller pre-folds log2e into the argument)
__device__ __forceinline__ float exp2_fast(float x) {
    float r;
    asm("v_exp_f32 %0, %1" : "=v"(r) : "v"(x));
    return r;
}

// VOP3P packed fp32: 2 FMAs / 2 muls per issue on 64-bit VGPR pairs
__device__ __forceinline__ f32x2 pk_fma(f32x2 a, f32x2 b, f32x2 c) {
    f32x2 d;
    asm("v_pk_fma_f32 %0, %1, %2, %3" : "=v"(d) : "v"(a), "v"(b), "v"(c));
    return d;
}
__device__ __forceinline__ f32x2 pk_mul(f32x2 a, f32x2 b) {
    f32x2 d;
    asm("v_pk_mul_f32 %0, %1, %2" : "=v"(d) : "v"(a), "v"(b));
    return d;
}

__device__ __forceinline__ void async16(const void* g, void* l) {
    __builtin_amdgcn_global_load_lds((const __attribute__((address_space(1))) void*)g,
                                     (__attribute__((address_space(3))) void*)l,
                                     16, 0, 0);
}

// ---------------------------------------------------------------------------
// K0: fp32 -> bf16 weight conversion, both weight matrices in one launch
// ---------------------------------------------------------------------------
__global__ __launch_bounds__(256) void k_cvt2(const float* __restrict__ s1,
                                              short* __restrict__ d1, int n1,
                                              const float* __restrict__ s2,
                                              short* __restrict__ d2, int n2) {
    int i = blockIdx.x * 256 + threadIdx.x;
    if (i < n1) {
        float4 v = ((const float4*)s1)[i];
        short4 o = { f2bf(v.x), f2bf(v.y), f2bf(v.z), f2bf(v.w) };
        ((short4*)d1)[i] = o;
    } else {
        int j = i - n1;
        if (j < n2) {
            float4 v = ((const float4*)s2)[j];
            short4 o = { f2bf(v.x), f2bf(v.y), f2bf(v.z), f2bf(v.w) };
            ((short4*)d2)[j] = o;
        }
    }
}

// ---------------------------------------------------------------------------
// K1: pos embedding (analytic; batch_params/has_velocity provably cancel) +
// residual + RMSNorm. res fp32, hidden bf16.
// ---------------------------------------------------------------------------
__global__ __launch_bounds__(256) void k_pos_rms(const float* __restrict__ x,
                                                 const float* __restrict__ norm_w,
                                                 float* __restrict__ res,
                                                 short* __restrict__ hidb) {
    int row = blockIdx.x;
    int l = row & (LL - 1);
    int d3 = l & 3;
    int w = (l >> 2) & 15;
    int h = l >> 6;
    float coord[3] = { h * (1.0f / 15.0f), w * (1.0f / 15.0f), d3 * (1.0f / 3.0f) };
    const float LOG1E4 = 9.210340371976184f;
    int t = threadIdx.x;
    float r[3];
    float s = 0.0f;
#pragma unroll
    for (int i = 0; i < 3; i++) {
        int j = t + i * 256;
        int c = j >> 8;
        int fp = j & 255;
        int f = fp & 127;
        float omega = __expf(-(f * (1.0f / 128.0f)) * LOG1E4);
        float arg = coord[c] * omega;
        float pv = (fp < 128) ? __sinf(arg) : __cosf(arg);
        float rv = x[(size_t)row * DD + j] + pv;
        r[i] = rv;
        s += rv * rv;
    }
#pragma unroll
    for (int off = 32; off; off >>= 1) s += __shfl_xor(s, off, 64);
    __shared__ float ls[4];
    if ((t & 63) == 0) ls[t >> 6] = s;
    __syncthreads();
    s = ls[0] + ls[1] + ls[2] + ls[3];
    float rs = rsqrtf(s * (1.0f / DD) + 1e-5f);
#pragma unroll
    for (int i = 0; i < 3; i++) {
        int j = t + i * 256;
        res[(size_t)row * DD + j] = r[i];
        hidb[(size_t)row * DD + j] = f2bf(r[i] * rs * norm_w[j]);
    }
}

// ---------------------------------------------------------------------------
// MFMA bf16 GEMM (NT), 128x128 tile, BK=32, 4 waves, async16 staging.
// EPI 1 (in_proj): +bias; n<768 -> C0 (b,t,d); n>=768 -> C1 (b,t,d).
// ---------------------------------------------------------------------------
template <int EPI, bool AF32>
__global__ __launch_bounds__(256) void gemm_mfma(const void* __restrict__ Ap,
                                                 const short* __restrict__ Bw,
                                                 int Kd,
                                                 const float* __restrict__ bias,
                                                 const float* __restrict__ resid,
                                                 float* __restrict__ C0,
                                                 float* __restrict__ C1) {
    __shared__ short As[4096];   // 128 rows x 32 k, fragment-ordered
    __shared__ short Bs[4096];
    int m0 = blockIdx.y * 128;
    int n0 = blockIdx.x * 128;
    int tid = threadIdx.x;
    int lane = tid & 63, wave = tid >> 6;
    int q = lane >> 4, r = lane & 15;
    int wm = wave >> 1, wn = wave & 1;

    const size_t Kb = (size_t)Kd * 2;
    const char* gB0 = (const char*)Bw + (size_t)(n0 + wave * 16 + r) * Kb + q * 16;
    const char* gB1 = gB0 + 64 * Kb;
    char* lB0 = (char*)Bs + wave * 1024;
    char* lB1 = lB0 + 4096;
    const char* gA0 = nullptr; const char* gA1 = nullptr;
    char* lA0 = nullptr; char* lA1 = nullptr;
    if (!AF32) {
        gA0 = (const char*)Ap + (size_t)(m0 + wave * 16 + r) * Kb + q * 16;
        gA1 = gA0 + 64 * Kb;
        lA0 = (char*)As + wave * 1024;
        lA1 = lA0 + 4096;
    }

    f32x4 acc[4][4] = {};

    for (int k0 = 0; k0 < Kd; k0 += 32) {
        if (AF32) {
            const float* Af = (const float*)Ap;
#pragma unroll
            for (int p = 0; p < 2; p++) {
                int m = m0 + (p * 4 + wave) * 16 + r;
                const float* src = Af + (size_t)m * Kd + k0 + q * 8;
                float4 v0 = *(const float4*)src;
                float4 v1 = *(const float4*)(src + 4);
                bf16x8 pk;
                pk[0] = f2bf(v0.x); pk[1] = f2bf(v0.y);
                pk[2] = f2bf(v0.z); pk[3] = f2bf(v0.w);
                pk[4] = f2bf(v1.x); pk[5] = f2bf(v1.y);
                pk[6] = f2bf(v1.z); pk[7] = f2bf(v1.w);
                *(bf16x8*)&As[p * 2048 + wave * 512 + lane * 8] = pk;
            }
        } else {
            async16(gA0, lA0); async16(gA1, lA1);
            gA0 += 64; gA1 += 64;
        }
        async16(gB0, lB0); async16(gB1, lB1);
        gB0 += 64; gB1 += 64;
        __syncthreads();
        bf16x8 af[4], bf[4];
#pragma unroll
        for (int a = 0; a < 4; a++)
            af[a] = *(const bf16x8*)&As[((wm * 4 + a) * 64 + q * 16 + r) * 8];
#pragma unroll
        for (int b = 0; b < 4; b++)
            bf[b] = *(const bf16x8*)&Bs[((wn * 4 + b) * 64 + q * 16 + r) * 8];
#pragma unroll
        for (int a = 0; a < 4; a++)
#pragma unroll
            for (int b = 0; b < 4; b++)
                acc[a][b] = __builtin_amdgcn_mfma_f32_16x16x32_bf16(
                    af[a], bf[b], acc[a][b], 0, 0, 0);
        __syncthreads();
    }

    // C/D layout: col(n) = lane&15, row(m) = (lane>>4)*4 + reg  [m89/m91]
#pragma unroll
    for (int a = 0; a < 4; a++) {
        int mrow = m0 + (wm * 4 + a) * 16 + q * 4;
#pragma unroll
        for (int b = 0; b < 4; b++) {
            int ncol = n0 + (wn * 4 + b) * 16 + r;
            float bb = bias[ncol];
            if (EPI == 1) {
                float* dst = (ncol < DD) ? (C0 + (size_t)mrow * DD + ncol)
                                         : (C1 + (size_t)mrow * DD + (ncol - DD));
#pragma unroll
                for (int e = 0; e < 4; e++)
                    dst[(size_t)e * DD] = acc[a][b][e] + bb;
            } else {
#pragma unroll
                for (int e = 0; e < 4; e++) {
                    size_t idx = (size_t)(mrow + e) * DD + ncol;
                    C0[idx] = acc[a][b][e] + bb + resid[idx];
                }
            }
        }
    }
}

// ---------------------------------------------------------------------------
// MFMA bf16 GEMM, 128m x 64n tile, BK=32, 4 waves (each 32m x 64n).
// out_proj dedicated: grid (12,64) = 768 blocks = 3/CU balanced.
// Epilogue: +bias +resid -> C0.
// ---------------------------------------------------------------------------
template <bool AF32>
__global__ __launch_bounds__(256) void gemm_mfma_n64(const void* __restrict__ Ap,
                                                     const short* __restrict__ Bw,
                                                     int Kd,
                                                     const float* __restrict__ bias,
                                                     const float* __restrict__ resid,
                                                     float* __restrict__ C0) {
    __shared__ short As[4096];   // 128 rows x 32 k, fragment-ordered (8 KB)
    __shared__ short Bs[2048];   // 64 rows x 32 k (4 KB)
    int m0 = blockIdx.y * 128;
    int n0 = blockIdx.x * 64;
    int tid = threadIdx.x;
    int lane = tid & 63, wave = tid >> 6;
    int q = lane >> 4, r = lane & 15;

    const size_t Kb = (size_t)Kd * 2;
    const char* gB0 = (const char*)Bw + (size_t)(n0 + wave * 16 + r) * Kb + q * 16;
    char* lB0 = (char*)Bs + wave * 1024;
    const char* gA0 = nullptr; const char* gA1 = nullptr;
    char* lA0 = nullptr; char* lA1 = nullptr;
    if (!AF32) {
        gA0 = (const char*)Ap + (size_t)(m0 + wave * 16 + r) * Kb + q * 16;
        gA1 = gA0 + 64 * Kb;
        lA0 = (char*)As + wave * 1024;
        lA1 = lA0 + 4096;
    }

    f32x4 acc[2][4] = {};

    for (int k0 = 0; k0 < Kd; k0 += 32) {
        if (AF32) {
            const float* Af = (const float*)Ap;
#pragma unroll
            for (int p = 0; p < 2; p++) {
                int m = m0 + (p * 4 + wave) * 16 + r;
                const float* src = Af + (size_t)m * Kd + k0 + q * 8;
                float4 v0 = *(const float4*)src;
                float4 v1 = *(const float4*)(src + 4);
                bf16x8 pk;
                pk[0] = f2bf(v0.x); pk[1] = f2bf(v0.y);
                pk[2] = f2bf(v0.z); pk[3] = f2bf(v0.w);
                pk[4] = f2bf(v1.x); pk[5] = f2bf(v1.y);
                pk[6] = f2bf(v1.z); pk[7] = f2bf(v1.w);
                *(bf16x8*)&As[p * 2048 + wave * 512 + lane * 8] = pk;
            }
        } else {
            async16(gA0, lA0); async16(gA1, lA1);
            gA0 += 64; gA1 += 64;
        }
        async16(gB0, lB0);
        gB0 += 64;
        __syncthreads();
        bf16x8 af[2], bf[4];
#pragma unroll
        for (int a = 0; a < 2; a++)
            af[a] = *(const bf16x8*)&As[((wave * 2 + a) * 64 + q * 16 + r) * 8];
#pragma unroll
        for (int b = 0; b < 4; b++)
            bf[b] = *(const bf16x8*)&Bs[(b * 64 + q * 16 + r) * 8];
#pragma unroll
        for (int a = 0; a < 2; a++)
#pragma unroll
            for (int b = 0; b < 4; b++)
                acc[a][b] = __builtin_amdgcn_mfma_f32_16x16x32_bf16(
                    af[a], bf[b], acc[a][b], 0, 0, 0);
        __syncthreads();
    }

#pragma unroll
    for (int a = 0; a < 2; a++) {
        int mrow = m0 + (wave * 2 + a) * 16 + q * 4;
#pragma unroll
        for (int b = 0; b < 4; b++) {
            int ncol = n0 + b * 16 + r;
            float bb = bias[ncol];
#pragma unroll
            for (int e = 0; e < 4; e++) {
                size_t idx = (size_t)(mrow + e) * DD + ncol;
                C0[idx] = acc[a][b][e] + bb + resid[idx];
            }
        }
    }
}

// ---------------------------------------------------------------------------
// K4: x_proj split-K GEMM. Tile 64m x 80n x 96k; grid (8,128) = 1024 blocks
// = 4/CU. Partials to per-chunk slices (plain stores); k_xred combines.
// ---------------------------------------------------------------------------
__global__ __launch_bounds__(256) void k_xproj(const float* __restrict__ A,
                                               const float* __restrict__ Bw,
                                               float* __restrict__ part) {
    __shared__ __align__(16) float As[16][68];
    __shared__ __align__(16) float Bs[16][84];
    int kbase = blockIdx.x * 96;
    int m0 = blockIdx.y * 64;
    int t = threadIdx.x;
    int tx = t & 15, ty = t >> 4;          // tx: 5 n-cols, ty: 4 m-rows
    int ar = t >> 2;
    int ak = (t & 3) * 4;
    float acc[4][5] = {};
    for (int k0 = kbase; k0 < kbase + 96; k0 += 16) {
        float4 av = *(const float4*)(A + (size_t)(m0 + ar) * DD + k0 + ak);
        As[ak + 0][ar] = av.x; As[ak + 1][ar] = av.y;
        As[ak + 2][ar] = av.z; As[ak + 3][ar] = av.w;
        for (int idx = t; idx < 320; idx += 256) {
            int row = idx >> 2, kq = (idx & 3) * 4;
            float4 bv = *(const float4*)(Bw + (size_t)row * DD + k0 + kq);
            Bs[kq + 0][row] = bv.x; Bs[kq + 1][row] = bv.y;
            Bs[kq + 2][row] = bv.z; Bs[kq + 3][row] = bv.w;
        }
        __syncthreads();
#pragma unroll
        for (int kk = 0; kk < 16; kk++) {
            float4 a4 = *(const float4*)&As[kk][ty * 4];
            float aa[4] = { a4.x, a4.y, a4.z, a4.w };
            float b0 = Bs[kk][tx * 5 + 0];
            float b1 = Bs[kk][tx * 5 + 1];
            float b2 = Bs[kk][tx * 5 + 2];
            float b3 = Bs[kk][tx * 5 + 3];
            float b4 = Bs[kk][tx * 5 + 4];
#pragma unroll
            for (int i = 0; i < 4; i++) {
                acc[i][0] += aa[i] * b0; acc[i][1] += aa[i] * b1;
                acc[i][2] += aa[i] * b2; acc[i][3] += aa[i] * b3;
                acc[i][4] += aa[i] * b4;
            }
        }
        __syncthreads();
    }
    float* dst = part + (size_t)blockIdx.x * (BB * LL * 80);
#pragma unroll
    for (int i = 0; i < 4; i++) {
        int m = m0 + ty * 4 + i;
#pragma unroll
        for (int j = 0; j < 5; j++)
            dst[(size_t)m * 80 + tx * 5 + j] = acc[i][j];
    }
}

// ---------------------------------------------------------------------------
// K4b: reduce the 8 split-K partials into xdbl. float4 per thread.
// ---------------------------------------------------------------------------
__global__ __launch_bounds__(256) void k_xred(const float* __restrict__ part,
                                              float* __restrict__ xdbl) {
    const size_t n4 = (size_t)BB * LL * 80 / 4;   // 163840
    size_t i = (size_t)blockIdx.x * 256 + threadIdx.x;
    if (i >= n4) return;
    const float4* p4 = (const float4*)part;
    float4 s = p4[i];
#pragma unroll
    for (int c = 1; c < 8; c++) {
        float4 v = p4[c * n4 + i];
        s.x += v.x; s.y += v.y; s.z += v.z; s.w += v.w;
    }
    ((float4*)xdbl)[i] = s;
}

// ---------------------------------------------------------------------------
// fp32 NT GEMM. MODE 0 (x_proj fallback): plain store with n<N guard.
// MODE 2 (dt_proj): softplus, float4 store to (b,t,d).
// ---------------------------------------------------------------------------
template <int MODE>
__global__ __launch_bounds__(256) void gemm_nt(const float* __restrict__ A, int lda,
                                               const float* __restrict__ Bw, int ldb,
                                               int N, int Kd,
                                               const float* __restrict__ bias,
                                               float* __restrict__ C0, int ldc) {
    __shared__ __align__(16) float As[16][68];
    __shared__ __align__(16) float Bs[16][68];
    int m0 = blockIdx.y * 64;
    int n0 = blockIdx.x * 64;
    int t = threadIdx.x;
    int tx = t & 15, ty = t >> 4;
    int ar = t >> 2;
    int ak = (t & 3) * 4;
    float acc[4][4] = {};
    for (int k0 = 0; k0 < Kd; k0 += 16) {
        float4 av = *(const float4*)(A + (size_t)(m0 + ar) * lda + k0 + ak);
        int brow = n0 + ar;
        if (brow >= N) brow = N - 1;
        float4 bv = *(const float4*)(Bw + (size_t)brow * ldb + k0 + ak);
        As[ak + 0][ar] = av.x; As[ak + 1][ar] = av.y;
        As[ak + 2][ar] = av.z; As[ak + 3][ar] = av.w;
        Bs[ak + 0][ar] = bv.x; Bs[ak + 1][ar] = bv.y;
        Bs[ak + 2][ar] = bv.z; Bs[ak + 3][ar] = bv.w;
        __syncthreads();
#pragma unroll
        for (int kk = 0; kk < 16; kk++) {
            float4 a4 = *(const float4*)&As[kk][ty * 4];
            float4 b4 = *(const float4*)&Bs[kk][tx * 4];
            float aa[4] = { a4.x, a4.y, a4.z, a4.w };
            float bb[4] = { b4.x, b4.y, b4.z, b4.w };
#pragma unroll
            for (int i = 0; i < 4; i++)
#pragma unroll
                for (int j = 0; j < 4; j++) acc[i][j] += aa[i] * bb[j];
        }
        __syncthreads();
    }
    if (MODE == 0) {
#pragma unroll
        for (int i = 0; i < 4; i++) {
            int m = m0 + ty * 4 + i;
#pragma unroll
            for (int j = 0; j < 4; j++) {
                int n = n0 + tx * 4 + j;
                if (n < N) C0[(size_t)m * ldc + n] = acc[i][j];
            }
        }
    } else {
        float4 bi = *(const float4*)(bias + n0 + tx * 4);
        float bl[4] = { bi.x, bi.y, bi.z, bi.w };
#pragma unroll
        for (int i = 0; i < 4; i++) {
            int m = m0 + ty * 4 + i;
            float v[4];
#pragma unroll
            for (int j = 0; j < 4; j++) {
                float u = acc[i][j] + bl[j];
                v[j] = (u > 20.0f) ? u : log1pf(__expf(u));
            }
            float4 o = { v[0], v[1], v[2], v[3] };
            *(float4*)(C0 + (size_t)m * DD + n0 + tx * 4) = o;
        }
    }
}

// ---------------------------------------------------------------------------
// K3: depthwise causal conv (K=4) + bias + silu, (b,t,d) -> (b,t,d).
// x4-vectorized: thread handles 4 consecutive d via float4 (G13).
// ---------------------------------------------------------------------------
__global__ __launch_bounds__(256) void k_conv(const float* __restrict__ xin,
                                              const float* __restrict__ cw,
                                              const float* __restrict__ cb,
                                              float* __restrict__ xc) {
    size_t g4 = (size_t)blockIdx.x * 256 + threadIdx.x;
    int d = (int)((g4 * 4) % DD);
    int bt = (int)(g4 * 4 / DD);
    int tt = bt & (LL - 1);
    const float* p = xin + (size_t)bt * DD + d;
    float4 zr = { 0.f, 0.f, 0.f, 0.f };
    float4 x0 = (tt >= 3) ? *(const float4*)(p - 3 * DD) : zr;
    float4 x1 = (tt >= 2) ? *(const float4*)(p - 2 * DD) : zr;
    float4 x2 = (tt >= 1) ? *(const float4*)(p - 1 * DD) : zr;
    float4 x3 = *(const float4*)p;
    const float4* cw4 = (const float4*)cw;
    float4 w0 = cw4[d + 0], w1 = cw4[d + 1], w2 = cw4[d + 2], w3 = cw4[d + 3];
    float4 cbv = *(const float4*)(cb + d);
    float4 o;
    o.x = silu_f(cbv.x + x0.x * w0.x + x1.x * w0.y + x2.x * w0.z + x3.x * w0.w);
    o.y = silu_f(cbv.y + x0.y * w1.x + x1.y * w1.y + x2.y * w1.z + x3.y * w1.w);
    o.z = silu_f(cbv.z + x0.z * w2.x + x1.z * w2.y + x2.z * w2.z + x3.z * w2.w);
    o.w = silu_f(cbv.w + x0.w * w3.x + x1.w * w3.y + x2.w * w3.z + x3.w * w3.w);
    *(float4*)(xc + g4 * 4) = o;
}

// ---------------------------------------------------------------------------
// K5: register-state chunked selective scan, v12 (v11 + unroll-4 phases).
// Partition: 32 chunks x 32 t, 8 d/block. Grid = 768 blocks = 3/CU, LDS
// 32 KB, XCD swizzle. 4-deep prefetch dt/xc(/z), 1-deep B/C.
// v12: phase 1 and phase 3 loops unrolled 4x (= the pipeline period) so the
// register rotations (dt/xc/z scalars + 8 float4 B/C copies, ~40 v_mov per
// i-step in the dynamic loop) become pure renames. VALUBusy was 55% with
// barely half of it useful math -- the rotation movs were the tax.
// exp = pre-scaled log2 + raw v_exp_f32; P via dtsum; states packed f32x2
// (VOP3P); y emitted bf16.
// ---------------------------------------------------------------------------
template <bool YB>
__global__ __launch_bounds__(256, 3) void k_scan(const float* __restrict__ dtf,
                                                 const float* __restrict__ xc,
                                                 const float* __restrict__ xdbl,
                                                 const float* __restrict__ A_log,
                                                 const float* __restrict__ Dp,
                                                 float* __restrict__ zy,
                                                 short* __restrict__ yb) {
    __shared__ float Pl[32 * 8 * 16];      // [c][d][n] 16 KB; becomes H
    __shared__ float Sl[32 * 8 * 16];      // 16 KB
    int bid = blockIdx.x;
    int xcd = bid & 7;                     // dispatch round-robins bid % 8
    int v = bid >> 3;                      // 0..95 within XCD
    int dtile = xcd * 12 + (v % 12);       // 12 contiguous d-tiles per XCD
    int b = v / 12;
    int d0 = dtile * 8;
    int tid = threadIdx.x;
    int dl = tid & 7;
    int c = tid >> 3;                      // chunk 0..31 (32 t each)
    int d = d0 + dl;

    const float LOG2E = 1.4426950408889634f;
    f32x2 Ac2[8];
    {
        const float4* al = (const float4*)(A_log + d * NNs);
#pragma unroll
        for (int i = 0; i < 4; i++) {
            float4 v4 = al[i];
            Ac2[i * 2]     = (f32x2){ -__expf(v4.x) * LOG2E, -__expf(v4.y) * LOG2E };
            Ac2[i * 2 + 1] = (f32x2){ -__expf(v4.z) * LOG2E, -__expf(v4.w) * LOG2E };
        }
    }
    size_t rb = ((size_t)(b * LL + c * 32)) * DD + d;
    const float* dtp = dtf + rb;
    const float* xcp = xc + rb;
    float* zp = zy + rb;
    short* ybp = yb + rb;
    const float* xrow = xdbl + ((size_t)(b * LL + c * 32)) * 80 + RR;

    // ---- Phase 1: local scan from zero state (4-deep dt/xc, 1-deep B)
    f32x2 S2[8];
#pragma unroll
    for (int k = 0; k < 8; k++) S2[k] = (f32x2){ 0.0f, 0.0f };
    float dtsum = 0.0f;
    {
        float dt0 = dtp[0],      xc0 = xcp[0];
        float dt1 = dtp[DD],     xc1 = xcp[DD];
        float dt2 = dtp[2 * DD], xc2 = xcp[2 * DD];
        float dt3 = dtp[3 * DD], xc3 = xcp[3 * DD];
        float4 Bb[4];
#pragma unroll
        for (int qq = 0; qq < 4; qq++) Bb[qq] = *(const float4*)(xrow + qq * 4);
#pragma unroll 4
        for (int i = 0; i < 32; i++) {
            int i4 = (i + 4 < 32) ? i + 4 : 31;
            int i1 = (i + 1 < 32) ? i + 1 : 31;
            float dtn = dtp[(size_t)i4 * DD];
            float xcn = xcp[(size_t)i4 * DD];
            float4 nB[4];
            const float* nBr = xrow + i1 * 80;
#pragma unroll
            for (int qq = 0; qq < 4; qq++) nB[qq] = *(const float4*)(nBr + qq * 4);

            float dx = dt0 * xc0;
            dtsum += dt0;
            f32x2 dtp2 = (f32x2){ dt0, dt0 };
            f32x2 dx2 = (f32x2){ dx, dx };
#pragma unroll
            for (int k = 0; k < 8; k++) {
                float4 qb = Bb[k >> 1];
                f32x2 bl2 = (k & 1) ? (f32x2){ qb.z, qb.w } : (f32x2){ qb.x, qb.y };
                f32x2 arg = pk_mul(dtp2, Ac2[k]);
                f32x2 e2;
                e2[0] = exp2_fast(arg[0]);
                e2[1] = exp2_fast(arg[1]);
                f32x2 dxb = pk_mul(dx2, bl2);
                S2[k] = pk_fma(e2, S2[k], dxb);
            }
            dt0 = dt1; dt1 = dt2; dt2 = dt3; dt3 = dtn;
            xc0 = xc1; xc1 = xc2; xc2 = xc3; xc3 = xcn;
#pragma unroll
            for (int qq = 0; qq < 4; qq++) Bb[qq] = nB[qq];
        }
    }
    {
        float* pw = &Pl[(c * 8 + dl) * 16];
        float* sw = &Sl[(c * 8 + dl) * 16];
#pragma unroll
        for (int q2 = 0; q2 < 4; q2++) {
            float4 pv = { exp2_fast(Ac2[q2 * 2][0] * dtsum),
                          exp2_fast(Ac2[q2 * 2][1] * dtsum),
                          exp2_fast(Ac2[q2 * 2 + 1][0] * dtsum),
                          exp2_fast(Ac2[q2 * 2 + 1][1] * dtsum) };
            float4 sv = { S2[q2 * 2][0], S2[q2 * 2][1],
                          S2[q2 * 2 + 1][0], S2[q2 * 2 + 1][1] };
            *(float4*)(pw + q2 * 4) = pv;
            *(float4*)(sw + q2 * 4) = sv;
        }
    }
    __syncthreads();
    // ---- Phase 2: serial combine, thread per (d,n); H overwrites Pl
    if (tid < 128) {
        int d2 = tid >> 4, n2 = tid & 15;
        float hh = 0.0f;
#pragma unroll
        for (int cc = 0; cc < 32; cc++) {
            int idx = (cc * 8 + d2) * 16 + n2;
            float Pv = Pl[idx], Sv = Sl[idx];
            Pl[idx] = hh;
            hh = Pv * hh + Sv;
        }
    }
    __syncthreads();
    f32x2 h2[8];
    {
        const float* hr = &Pl[(c * 8 + dl) * 16];
#pragma unroll
        for (int q2 = 0; q2 < 4; q2++) {
            float4 v4 = *(const float4*)(hr + q2 * 4);
            h2[q2 * 2]     = (f32x2){ v4.x, v4.y };
            h2[q2 * 2 + 1] = (f32x2){ v4.z, v4.w };
        }
    }
    float Dv = Dp[d];
    // ---- Phase 3: rescan from h_in, gate, write (4-deep dt/xc/z, 1-deep B/C)
    {
        float dt0 = dtp[0],      xc0 = xcp[0],      zv0 = zp[0];
        float dt1 = dtp[DD],     xc1 = xcp[DD],     zv1 = zp[DD];
        float dt2 = dtp[2 * DD], xc2 = xcp[2 * DD], zv2 = zp[2 * DD];
        float dt3 = dtp[3 * DD], xc3 = xcp[3 * DD], zv3 = zp[3 * DD];
        float4 Bb[4], Cc[4];
#pragma unroll
        for (int qq = 0; qq < 4; qq++) {
            Bb[qq] = *(const float4*)(xrow + qq * 4);
            Cc[qq] = *(const float4*)(xrow + 16 + qq * 4);
        }
#pragma unroll 4
        for (int i = 0; i < 32; i++) {
            int i4 = (i + 4 < 32) ? i + 4 : 31;
            int i1 = (i + 1 < 32) ? i + 1 : 31;
            float dtn = dtp[(size_t)i4 * DD];
            float xcn = xcp[(size_t)i4 * DD];
            float zvn = zp[(size_t)i4 * DD];
            float4 nB[4], nC[4];
            const float* nBr = xrow + i1 * 80;
#pragma unroll
            for (int qq = 0; qq < 4; qq++) {
                nB[qq] = *(const float4*)(nBr + qq * 4);
                nC[qq] = *(const float4*)(nBr + 16 + qq * 4);
            }
            float dx = dt0 * xc0;
            f32x2 dtp2 = (f32x2){ dt0, dt0 };
            f32x2 dx2 = (f32x2){ dx, dx };
            f32x2 y2 = (f32x2){ Dv * xc0, 0.0f };
#pragma unroll
            for (int k = 0; k < 8; k++) {
                float4 qb = Bb[k >> 1];
                float4 qc = Cc[k >> 1];
                f32x2 bl2 = (k & 1) ? (f32x2){ qb.z, qb.w } : (f32x2){ qb.x, qb.y };
                f32x2 cl2 = (k & 1) ? (f32x2){ qc.z, qc.w } : (f32x2){ qc.x, qc.y };
                f32x2 arg = pk_mul(dtp2, Ac2[k]);
                f32x2 e2;
                e2[0] = exp2_fast(arg[0]);
                e2[1] = exp2_fast(arg[1]);
                f32x2 dxb = pk_mul(dx2, bl2);
                h2[k] = pk_fma(e2, h2[k], dxb);
                y2 = pk_fma(h2[k], cl2, y2);
            }
            float y = y2[0] + y2[1];
            float gated = y * silu_f(zv0);
            if (YB) ybp[(size_t)i * DD] = f2bf(gated);
            else    zp[(size_t)i * DD] = gated;
            dt0 = dt1; dt1 = dt2; dt2 = dt3; dt3 = dtn;
            xc0 = xc1; xc1 = xc2; xc2 = xc3; xc3 = xcn;
            zv0 = zv1; zv1 = zv2; zv2 = zv3; zv3 = zvn;
#pragma unroll
            for (int qq = 0; qq < 4; qq++) { Bb[qq] = nB[qq]; Cc[qq] = nC[qq]; }
        }
    }
}

// ---------------------------------------------------------------------------
extern "C" void kernel_launch(void* const* d_in, const int* in_sizes, int n_in,
                              void* d_out, int out_size, void* d_ws, size_t ws_size,
                              hipStream_t stream) {
    const float* x      = (const float*)d_in[0];
    // d_in[1] batch_params, d_in[2] has_velocity: provably no effect
    const float* norm_w = (const float*)d_in[3];
    const float* in_w   = (const float*)d_in[4];
    const float* in_b   = (const float*)d_in[5];
    const float* conv_w = (const float*)d_in[6];
    const float* conv_b = (const float*)d_in[7];
    const float* xp_w   = (const float*)d_in[8];
    const float* dt_w   = (const float*)d_in[9];
    const float* dt_b   = (const float*)d_in[10];
    const float* A_log  = (const float*)d_in[11];
    const float* Dp     = (const float*)d_in[12];
    const float* out_w  = (const float*)d_in[13];
    const float* out_b  = (const float*)d_in[14];
    float* out = (float*)d_out;

    const size_t S = (size_t)BB * LL * DD;     // 6291456
    const size_t X = (size_t)BB * LL * 80;     // 655360
    float* res   = (float*)d_ws;               // residual (fp32)
    float* slotA = res + S;                    // hidb (bf16) then xc (fp32)
    float* slotB = slotA + S;                  // xin then dtf (fp32)
    float* zf    = slotB + S;                  // z (b,t,d)
    float* xdbl  = zf + S;                     // (B*L, 80)
    short* inw_b  = (short*)(xdbl + X);                      // 1536x768 bf16
    short* outw_b = inw_b + 1536 * DD;                       // 768x768 bf16
    short* ybf    = outw_b + DD * DD;                        // gated y bf16
    float* xpart  = (float*)(ybf + S);                       // 8 x (B*L,80)

    short* hidb = (short*)slotA;
    float* xc   = slotA;
    float* xin  = slotB;
    float* dtf  = slotB;

    const int M = BB * LL;                     // 8192

    // workspace guards
    size_t needYB = (size_t)((char*)(ybf + S) - (char*)d_ws);
    size_t needXP = (size_t)((char*)(xpart + 8 * X) - (char*)d_ws);
    bool useYB = ws_size >= needYB;
    bool useXP = ws_size >= needXP;

    // 0. weight conversions (one launch)
    {
        int n1 = 1536 * DD / 4, n2 = DD * DD / 4;
        k_cvt2<<<(n1 + n2 + 255) / 256, 256, 0, stream>>>(in_w, inw_b, n1,
                                                          out_w, outw_b, n2);
    }

    // 1. pos + residual + rmsnorm (hidden bf16)
    k_pos_rms<<<M, 256, 0, stream>>>(x, norm_w, res, hidb);

    // 2. in_proj (MFMA): -> xin (b,t,d) | zf (b,t,d)
    gemm_mfma<1, false><<<dim3(1536 / 128, M / 128), 256, 0, stream>>>(
        hidb, inw_b, DD, in_b, nullptr, xin, zf);

    // 3. depthwise conv + silu: xin -> xc (x4-vectorized)
    k_conv<<<(int)(S / 1024), 256, 0, stream>>>(xin, conv_w, conv_b, xc);

    // 4. x_proj: split-K partials + reduce (no atomics); fallback gemm_nt
    if (useXP) {
        k_xproj<<<dim3(8, M / 64), 256, 0, stream>>>(xc, xp_w, xpart);
        k_xred<<<(int)(X / 4 + 255) / 256, 256, 0, stream>>>(xpart, xdbl);
    } else {
        gemm_nt<0><<<dim3(2, M / 64), 256, 0, stream>>>(
            xc, DD, xp_w, DD, RR + 2 * NNs, DD, nullptr, xdbl, 80);
    }

    // 5. dt_proj + softplus -> dtf (b,t,d) (reuses slotB; xin dead)
    gemm_nt<2><<<dim3(DD / 64, M / 64), 256, 0, stream>>>(
        xdbl, 80, dt_w, RR, DD, RR, dt_b, dtf, DD);

    // 6. scan + gating; 7. out_proj (128x64 tile, 768 blocks balanced)
    if (useYB) {
        k_scan<true><<<768, 256, 0, stream>>>(dtf, xc, xdbl, A_log, Dp, zf, ybf);
        gemm_mfma_n64<false><<<dim3(DD / 64, M / 128), 256, 0, stream>>>(
            ybf, outw_b, DD, out_b, res, out);
    } else {
        k_scan<false><<<768, 256, 0, stream>>>(dtf, xc, xdbl, A_log, Dp, zf, ybf);
        gemm_mfma_n64<true><<<dim3(DD / 64, M / 128), 256, 0, stream>>>(
            zf, outw_b, DD, out_b, res, out);
    }
}

// Round 14
// 327.114 us; speedup vs baseline: 1.0394x; 1.0394x over previous
//
#include <hip/hip_runtime.h>
#include <math.h>

#define BB 8
#define LL 1024
#define DD 768
#define NNs 16
#define RR 48

typedef __attribute__((ext_vector_type(8))) short bf16x8;
typedef __attribute__((ext_vector_type(4))) float f32x4;
typedef __attribute__((ext_vector_type(2))) float f32x2;

__device__ __forceinline__ float silu_f(float v) { return v / (1.0f + __expf(-v)); }

__device__ __forceinline__ short f2bf(float f) {
    union { float f; unsigned u; } v; v.f = f;
    unsigned r = (v.u + 0x7fffu + ((v.u >> 16) & 1u)) >> 16;
    return (short)r;
}

// raw v_exp_f32: computes 2^x (caller pre-folds log2e into the argument)
__device__ __forceinline__ float exp2_fast(float x) {
    float r;
    asm("v_exp_f32 %0, %1" : "=v"(r) : "v"(x));
    return r;
}

// VOP3P packed fp32: 2 FMAs / 2 muls per issue on 64-bit VGPR pairs
__device__ __forceinline__ f32x2 pk_fma(f32x2 a, f32x2 b, f32x2 c) {
    f32x2 d;
    asm("v_pk_fma_f32 %0, %1, %2, %3" : "=v"(d) : "v"(a), "v"(b), "v"(c));
    return d;
}
__device__ __forceinline__ f32x2 pk_mul(f32x2 a, f32x2 b) {
    f32x2 d;
    asm("v_pk_mul_f32 %0, %1, %2" : "=v"(d) : "v"(a), "v"(b));
    return d;
}

__device__ __forceinline__ void async16(const void* g, void* l) {
    __builtin_amdgcn_global_load_lds((const __attribute__((address_space(1))) void*)g,
                                     (__attribute__((address_space(3))) void*)l,
                                     16, 0, 0);
}

// ---------------------------------------------------------------------------
// K0: fp32 -> bf16 weight conversion, both weight matrices in one launch
// ---------------------------------------------------------------------------
__global__ __launch_bounds__(256) void k_cvt2(const float* __restrict__ s1,
                                              short* __restrict__ d1, int n1,
                                              const float* __restrict__ s2,
                                              short* __restrict__ d2, int n2) {
    int i = blockIdx.x * 256 + threadIdx.x;
    if (i < n1) {
        float4 v = ((const float4*)s1)[i];
        short4 o = { f2bf(v.x), f2bf(v.y), f2bf(v.z), f2bf(v.w) };
        ((short4*)d1)[i] = o;
    } else {
        int j = i - n1;
        if (j < n2) {
            float4 v = ((const float4*)s2)[j];
            short4 o = { f2bf(v.x), f2bf(v.y), f2bf(v.z), f2bf(v.w) };
            ((short4*)d2)[j] = o;
        }
    }
}

// ---------------------------------------------------------------------------
// K1: pos embedding (analytic; batch_params/has_velocity provably cancel) +
// residual + RMSNorm. res fp32, hidden bf16.
// ---------------------------------------------------------------------------
__global__ __launch_bounds__(256) void k_pos_rms(const float* __restrict__ x,
                                                 const float* __restrict__ norm_w,
                                                 float* __restrict__ res,
                                                 short* __restrict__ hidb) {
    int row = blockIdx.x;
    int l = row & (LL - 1);
    int d3 = l & 3;
    int w = (l >> 2) & 15;
    int h = l >> 6;
    float coord[3] = { h * (1.0f / 15.0f), w * (1.0f / 15.0f), d3 * (1.0f / 3.0f) };
    const float LOG1E4 = 9.210340371976184f;
    int t = threadIdx.x;
    float r[3];
    float s = 0.0f;
#pragma unroll
    for (int i = 0; i < 3; i++) {
        int j = t + i * 256;
        int c = j >> 8;
        int fp = j & 255;
        int f = fp & 127;
        float omega = __expf(-(f * (1.0f / 128.0f)) * LOG1E4);
        float arg = coord[c] * omega;
        float pv = (fp < 128) ? __sinf(arg) : __cosf(arg);
        float rv = x[(size_t)row * DD + j] + pv;
        r[i] = rv;
        s += rv * rv;
    }
#pragma unroll
    for (int off = 32; off; off >>= 1) s += __shfl_xor(s, off, 64);
    __shared__ float ls[4];
    if ((t & 63) == 0) ls[t >> 6] = s;
    __syncthreads();
    s = ls[0] + ls[1] + ls[2] + ls[3];
    float rs = rsqrtf(s * (1.0f / DD) + 1e-5f);
#pragma unroll
    for (int i = 0; i < 3; i++) {
        int j = t + i * 256;
        res[(size_t)row * DD + j] = r[i];
        hidb[(size_t)row * DD + j] = f2bf(r[i] * rs * norm_w[j]);
    }
}

// ---------------------------------------------------------------------------
// in_proj MFMA bf16 GEMM (NT), 128x128 tile, BK=64, 4 waves, async16.
// Half the barrier drains of the BK=32 loop (12 iters vs 24); LDS 32 KB
// (grid-limited 3/CU anyway). LDS layout [rowblk16][kc0..7][r]x16B; staging
// issue (p half, off in {0,4}) writes wave-contiguous 1 KB; MFMA kk in {0,1}
// reads chunks kk*4+q. Epilogue: +bias; n<768 -> C0; n>=768 -> C1.
// ---------------------------------------------------------------------------
__global__ __launch_bounds__(256) void gemm_in64(const short* __restrict__ Ap,
                                                 const short* __restrict__ Bw,
                                                 const float* __restrict__ bias,
                                                 float* __restrict__ C0,
                                                 float* __restrict__ C1) {
    __shared__ short As[8192];   // 128 rows x 64 k (16 KB)
    __shared__ short Bs[8192];
    int m0 = blockIdx.y * 128;
    int n0 = blockIdx.x * 128;
    int tid = threadIdx.x;
    int lane = tid & 63, wave = tid >> 6;
    int q = lane >> 4, r = lane & 15;
    int wm = wave >> 1, wn = wave & 1;

    const size_t Kb = (size_t)DD * 2;
    const char* gA[4]; char* lA[4];
    const char* gB[4]; char* lB[4];
#pragma unroll
    for (int p = 0; p < 2; p++)
#pragma unroll
        for (int o = 0; o < 2; o++) {
            int idx = p * 2 + o;
            gA[idx] = (const char*)Ap + (size_t)(m0 + p * 64 + wave * 16 + r) * Kb
                      + (o * 4 + q) * 16;
            gB[idx] = (const char*)Bw + (size_t)(n0 + p * 64 + wave * 16 + r) * Kb
                      + (o * 4 + q) * 16;
            lA[idx] = (char*)As + (p * 4 + wave) * 2048 + o * 1024;
            lB[idx] = (char*)Bs + (p * 4 + wave) * 2048 + o * 1024;
        }

    f32x4 acc[4][4] = {};

    for (int k0 = 0; k0 < DD; k0 += 64) {
#pragma unroll
        for (int idx = 0; idx < 4; idx++) {
            async16(gA[idx], lA[idx]);
            async16(gB[idx], lB[idx]);
            gA[idx] += 128; gB[idx] += 128;
        }
        __syncthreads();
#pragma unroll
        for (int kk = 0; kk < 2; kk++) {
            bf16x8 af[4], bf[4];
#pragma unroll
            for (int a = 0; a < 4; a++)
                af[a] = *(const bf16x8*)&As[((wm * 4 + a) * 128 + (kk * 4 + q) * 16 + r) * 8];
#pragma unroll
            for (int b = 0; b < 4; b++)
                bf[b] = *(const bf16x8*)&Bs[((wn * 4 + b) * 128 + (kk * 4 + q) * 16 + r) * 8];
#pragma unroll
            for (int a = 0; a < 4; a++)
#pragma unroll
                for (int b = 0; b < 4; b++)
                    acc[a][b] = __builtin_amdgcn_mfma_f32_16x16x32_bf16(
                        af[a], bf[b], acc[a][b], 0, 0, 0);
        }
        __syncthreads();
    }

    // C/D layout: col(n) = lane&15, row(m) = (lane>>4)*4 + reg  [m89/m91]
#pragma unroll
    for (int a = 0; a < 4; a++) {
        int mrow = m0 + (wm * 4 + a) * 16 + q * 4;
#pragma unroll
        for (int b = 0; b < 4; b++) {
            int ncol = n0 + (wn * 4 + b) * 16 + r;
            float bb = bias[ncol];
            float* dst = (ncol < DD) ? (C0 + (size_t)mrow * DD + ncol)
                                     : (C1 + (size_t)mrow * DD + (ncol - DD));
#pragma unroll
            for (int e = 0; e < 4; e++)
                dst[(size_t)e * DD] = acc[a][b][e] + bb;
        }
    }
}

// ---------------------------------------------------------------------------
// MFMA bf16 GEMM, 128m x 64n tile, BK=32, 4 waves (each 32m x 64n).
// out_proj dedicated: grid (12,64) = 768 blocks = 3/CU balanced.
// Epilogue: +bias +resid -> C0.
// ---------------------------------------------------------------------------
template <bool AF32>
__global__ __launch_bounds__(256) void gemm_mfma_n64(const void* __restrict__ Ap,
                                                     const short* __restrict__ Bw,
                                                     int Kd,
                                                     const float* __restrict__ bias,
                                                     const float* __restrict__ resid,
                                                     float* __restrict__ C0) {
    __shared__ short As[4096];   // 128 rows x 32 k, fragment-ordered (8 KB)
    __shared__ short Bs[2048];   // 64 rows x 32 k (4 KB)
    int m0 = blockIdx.y * 128;
    int n0 = blockIdx.x * 64;
    int tid = threadIdx.x;
    int lane = tid & 63, wave = tid >> 6;
    int q = lane >> 4, r = lane & 15;

    const size_t Kb = (size_t)Kd * 2;
    const char* gB0 = (const char*)Bw + (size_t)(n0 + wave * 16 + r) * Kb + q * 16;
    char* lB0 = (char*)Bs + wave * 1024;
    const char* gA0 = nullptr; const char* gA1 = nullptr;
    char* lA0 = nullptr; char* lA1 = nullptr;
    if (!AF32) {
        gA0 = (const char*)Ap + (size_t)(m0 + wave * 16 + r) * Kb + q * 16;
        gA1 = gA0 + 64 * Kb;
        lA0 = (char*)As + wave * 1024;
        lA1 = lA0 + 4096;
    }

    f32x4 acc[2][4] = {};

    for (int k0 = 0; k0 < Kd; k0 += 32) {
        if (AF32) {
            const float* Af = (const float*)Ap;
#pragma unroll
            for (int p = 0; p < 2; p++) {
                int m = m0 + (p * 4 + wave) * 16 + r;
                const float* src = Af + (size_t)m * Kd + k0 + q * 8;
                float4 v0 = *(const float4*)src;
                float4 v1 = *(const float4*)(src + 4);
                bf16x8 pk;
                pk[0] = f2bf(v0.x); pk[1] = f2bf(v0.y);
                pk[2] = f2bf(v0.z); pk[3] = f2bf(v0.w);
                pk[4] = f2bf(v1.x); pk[5] = f2bf(v1.y);
                pk[6] = f2bf(v1.z); pk[7] = f2bf(v1.w);
                *(bf16x8*)&As[p * 2048 + wave * 512 + lane * 8] = pk;
            }
        } else {
            async16(gA0, lA0); async16(gA1, lA1);
            gA0 += 64; gA1 += 64;
        }
        async16(gB0, lB0);
        gB0 += 64;
        __syncthreads();
        bf16x8 af[2], bf[4];
#pragma unroll
        for (int a = 0; a < 2; a++)
            af[a] = *(const bf16x8*)&As[((wave * 2 + a) * 64 + q * 16 + r) * 8];
#pragma unroll
        for (int b = 0; b < 4; b++)
            bf[b] = *(const bf16x8*)&Bs[(b * 64 + q * 16 + r) * 8];
#pragma unroll
        for (int a = 0; a < 2; a++)
#pragma unroll
            for (int b = 0; b < 4; b++)
                acc[a][b] = __builtin_amdgcn_mfma_f32_16x16x32_bf16(
                    af[a], bf[b], acc[a][b], 0, 0, 0);
        __syncthreads();
    }

#pragma unroll
    for (int a = 0; a < 2; a++) {
        int mrow = m0 + (wave * 2 + a) * 16 + q * 4;
#pragma unroll
        for (int b = 0; b < 4; b++) {
            int ncol = n0 + b * 16 + r;
            float bb = bias[ncol];
#pragma unroll
            for (int e = 0; e < 4; e++) {
                size_t idx = (size_t)(mrow + e) * DD + ncol;
                C0[idx] = acc[a][b][e] + bb + resid[idx];
            }
        }
    }
}

// ---------------------------------------------------------------------------
// K4: x_proj split-K GEMM. Tile 64m x 80n x 96k; grid (8,128) = 1024 blocks
// = 4/CU. Partials to per-chunk slices (plain stores); k_xred combines.
// ---------------------------------------------------------------------------
__global__ __launch_bounds__(256) void k_xproj(const float* __restrict__ A,
                                               const float* __restrict__ Bw,
                                               float* __restrict__ part) {
    __shared__ __align__(16) float As[16][68];
    __shared__ __align__(16) float Bs[16][84];
    int kbase = blockIdx.x * 96;
    int m0 = blockIdx.y * 64;
    int t = threadIdx.x;
    int tx = t & 15, ty = t >> 4;          // tx: 5 n-cols, ty: 4 m-rows
    int ar = t >> 2;
    int ak = (t & 3) * 4;
    float acc[4][5] = {};
    for (int k0 = kbase; k0 < kbase + 96; k0 += 16) {
        float4 av = *(const float4*)(A + (size_t)(m0 + ar) * DD + k0 + ak);
        As[ak + 0][ar] = av.x; As[ak + 1][ar] = av.y;
        As[ak + 2][ar] = av.z; As[ak + 3][ar] = av.w;
        for (int idx = t; idx < 320; idx += 256) {
            int row = idx >> 2, kq = (idx & 3) * 4;
            float4 bv = *(const float4*)(Bw + (size_t)row * DD + k0 + kq);
            Bs[kq + 0][row] = bv.x; Bs[kq + 1][row] = bv.y;
            Bs[kq + 2][row] = bv.z; Bs[kq + 3][row] = bv.w;
        }
        __syncthreads();
#pragma unroll
        for (int kk = 0; kk < 16; kk++) {
            float4 a4 = *(const float4*)&As[kk][ty * 4];
            float aa[4] = { a4.x, a4.y, a4.z, a4.w };
            float b0 = Bs[kk][tx * 5 + 0];
            float b1 = Bs[kk][tx * 5 + 1];
            float b2 = Bs[kk][tx * 5 + 2];
            float b3 = Bs[kk][tx * 5 + 3];
            float b4 = Bs[kk][tx * 5 + 4];
#pragma unroll
            for (int i = 0; i < 4; i++) {
                acc[i][0] += aa[i] * b0; acc[i][1] += aa[i] * b1;
                acc[i][2] += aa[i] * b2; acc[i][3] += aa[i] * b3;
                acc[i][4] += aa[i] * b4;
            }
        }
        __syncthreads();
    }
    float* dst = part + (size_t)blockIdx.x * (BB * LL * 80);
#pragma unroll
    for (int i = 0; i < 4; i++) {
        int m = m0 + ty * 4 + i;
#pragma unroll
        for (int j = 0; j < 5; j++)
            dst[(size_t)m * 80 + tx * 5 + j] = acc[i][j];
    }
}

// ---------------------------------------------------------------------------
// K4b: reduce the 8 split-K partials into xdbl. float4 per thread.
// ---------------------------------------------------------------------------
__global__ __launch_bounds__(256) void k_xred(const float* __restrict__ part,
                                              float* __restrict__ xdbl) {
    const size_t n4 = (size_t)BB * LL * 80 / 4;   // 163840
    size_t i = (size_t)blockIdx.x * 256 + threadIdx.x;
    if (i >= n4) return;
    const float4* p4 = (const float4*)part;
    float4 s = p4[i];
#pragma unroll
    for (int c = 1; c < 8; c++) {
        float4 v = p4[c * n4 + i];
        s.x += v.x; s.y += v.y; s.z += v.z; s.w += v.w;
    }
    ((float4*)xdbl)[i] = s;
}

// ---------------------------------------------------------------------------
// fp32 NT GEMM. MODE 0 (x_proj fallback): plain store with n<N guard.
// MODE 2 (dt_proj): softplus, float4 store to (b,t,d).
// ---------------------------------------------------------------------------
template <int MODE>
__global__ __launch_bounds__(256) void gemm_nt(const float* __restrict__ A, int lda,
                                               const float* __restrict__ Bw, int ldb,
                                               int N, int Kd,
                                               const float* __restrict__ bias,
                                               float* __restrict__ C0, int ldc) {
    __shared__ __align__(16) float As[16][68];
    __shared__ __align__(16) float Bs[16][68];
    int m0 = blockIdx.y * 64;
    int n0 = blockIdx.x * 64;
    int t = threadIdx.x;
    int tx = t & 15, ty = t >> 4;
    int ar = t >> 2;
    int ak = (t & 3) * 4;
    float acc[4][4] = {};
    for (int k0 = 0; k0 < Kd; k0 += 16) {
        float4 av = *(const float4*)(A + (size_t)(m0 + ar) * lda + k0 + ak);
        int brow = n0 + ar;
        if (brow >= N) brow = N - 1;
        float4 bv = *(const float4*)(Bw + (size_t)brow * ldb + k0 + ak);
        As[ak + 0][ar] = av.x; As[ak + 1][ar] = av.y;
        As[ak + 2][ar] = av.z; As[ak + 3][ar] = av.w;
        Bs[ak + 0][ar] = bv.x; Bs[ak + 1][ar] = bv.y;
        Bs[ak + 2][ar] = bv.z; Bs[ak + 3][ar] = bv.w;
        __syncthreads();
#pragma unroll
        for (int kk = 0; kk < 16; kk++) {
            float4 a4 = *(const float4*)&As[kk][ty * 4];
            float4 b4 = *(const float4*)&Bs[kk][tx * 4];
            float aa[4] = { a4.x, a4.y, a4.z, a4.w };
            float bb[4] = { b4.x, b4.y, b4.z, b4.w };
#pragma unroll
            for (int i = 0; i < 4; i++)
#pragma unroll
                for (int j = 0; j < 4; j++) acc[i][j] += aa[i] * bb[j];
        }
        __syncthreads();
    }
    if (MODE == 0) {
#pragma unroll
        for (int i = 0; i < 4; i++) {
            int m = m0 + ty * 4 + i;
#pragma unroll
            for (int j = 0; j < 4; j++) {
                int n = n0 + tx * 4 + j;
                if (n < N) C0[(size_t)m * ldc + n] = acc[i][j];
            }
        }
    } else {
        float4 bi = *(const float4*)(bias + n0 + tx * 4);
        float bl[4] = { bi.x, bi.y, bi.z, bi.w };
#pragma unroll
        for (int i = 0; i < 4; i++) {
            int m = m0 + ty * 4 + i;
            float v[4];
#pragma unroll
            for (int j = 0; j < 4; j++) {
                float u = acc[i][j] + bl[j];
                v[j] = (u > 20.0f) ? u : log1pf(__expf(u));
            }
            float4 o = { v[0], v[1], v[2], v[3] };
            *(float4*)(C0 + (size_t)m * DD + n0 + tx * 4) = o;
        }
    }
}

// ---------------------------------------------------------------------------
// K3: depthwise causal conv (K=4) + bias + silu, (b,t,d) -> (b,t,d).
// x4-vectorized: thread handles 4 consecutive d via float4 (G13).
// ---------------------------------------------------------------------------
__global__ __launch_bounds__(256) void k_conv(const float* __restrict__ xin,
                                              const float* __restrict__ cw,
                                              const float* __restrict__ cb,
                                              float* __restrict__ xc) {
    size_t g4 = (size_t)blockIdx.x * 256 + threadIdx.x;
    int d = (int)((g4 * 4) % DD);
    int bt = (int)(g4 * 4 / DD);
    int tt = bt & (LL - 1);
    const float* p = xin + (size_t)bt * DD + d;
    float4 zr = { 0.f, 0.f, 0.f, 0.f };
    float4 x0 = (tt >= 3) ? *(const float4*)(p - 3 * DD) : zr;
    float4 x1 = (tt >= 2) ? *(const float4*)(p - 2 * DD) : zr;
    float4 x2 = (tt >= 1) ? *(const float4*)(p - 1 * DD) : zr;
    float4 x3 = *(const float4*)p;
    const float4* cw4 = (const float4*)cw;
    float4 w0 = cw4[d + 0], w1 = cw4[d + 1], w2 = cw4[d + 2], w3 = cw4[d + 3];
    float4 cbv = *(const float4*)(cb + d);
    float4 o;
    o.x = silu_f(cbv.x + x0.x * w0.x + x1.x * w0.y + x2.x * w0.z + x3.x * w0.w);
    o.y = silu_f(cbv.y + x0.y * w1.x + x1.y * w1.y + x2.y * w1.z + x3.y * w1.w);
    o.z = silu_f(cbv.z + x0.z * w2.x + x1.z * w2.y + x2.z * w2.z + x3.z * w2.w);
    o.w = silu_f(cbv.w + x0.w * w3.x + x1.w * w3.y + x2.w * w3.z + x3.w * w3.w);
    *(float4*)(xc + g4 * 4) = o;
}

// ---------------------------------------------------------------------------
// K5: register-state chunked selective scan, v11 (round-12 state; the
// unroll-4 of v12 regressed 60->64 and is reverted).
// Partition: 32 chunks x 32 t, 8 d/block. Grid = 768 blocks = 3/CU, LDS
// 32 KB, XCD swizzle. 4-deep prefetch dt/xc(/z), 1-deep B/C; exp =
// pre-scaled log2 + raw v_exp_f32; P via dtsum; states packed f32x2
// (VOP3P); y emitted bf16.
// ---------------------------------------------------------------------------
template <bool YB>
__global__ __launch_bounds__(256, 3) void k_scan(const float* __restrict__ dtf,
                                                 const float* __restrict__ xc,
                                                 const float* __restrict__ xdbl,
                                                 const float* __restrict__ A_log,
                                                 const float* __restrict__ Dp,
                                                 float* __restrict__ zy,
                                                 short* __restrict__ yb) {
    __shared__ float Pl[32 * 8 * 16];      // [c][d][n] 16 KB; becomes H
    __shared__ float Sl[32 * 8 * 16];      // 16 KB
    int bid = blockIdx.x;
    int xcd = bid & 7;                     // dispatch round-robins bid % 8
    int v = bid >> 3;                      // 0..95 within XCD
    int dtile = xcd * 12 + (v % 12);       // 12 contiguous d-tiles per XCD
    int b = v / 12;
    int d0 = dtile * 8;
    int tid = threadIdx.x;
    int dl = tid & 7;
    int c = tid >> 3;                      // chunk 0..31 (32 t each)
    int d = d0 + dl;

    const float LOG2E = 1.4426950408889634f;
    f32x2 Ac2[8];
    {
        const float4* al = (const float4*)(A_log + d * NNs);
#pragma unroll
        for (int i = 0; i < 4; i++) {
            float4 v4 = al[i];
            Ac2[i * 2]     = (f32x2){ -__expf(v4.x) * LOG2E, -__expf(v4.y) * LOG2E };
            Ac2[i * 2 + 1] = (f32x2){ -__expf(v4.z) * LOG2E, -__expf(v4.w) * LOG2E };
        }
    }
    size_t rb = ((size_t)(b * LL + c * 32)) * DD + d;
    const float* dtp = dtf + rb;
    const float* xcp = xc + rb;
    float* zp = zy + rb;
    short* ybp = yb + rb;
    const float* xrow = xdbl + ((size_t)(b * LL + c * 32)) * 80 + RR;

    // ---- Phase 1: local scan from zero state (4-deep dt/xc, 1-deep B)
    f32x2 S2[8];
#pragma unroll
    for (int k = 0; k < 8; k++) S2[k] = (f32x2){ 0.0f, 0.0f };
    float dtsum = 0.0f;
    {
        float dt0 = dtp[0],      xc0 = xcp[0];
        float dt1 = dtp[DD],     xc1 = xcp[DD];
        float dt2 = dtp[2 * DD], xc2 = xcp[2 * DD];
        float dt3 = dtp[3 * DD], xc3 = xcp[3 * DD];
        float4 Bb[4];
#pragma unroll
        for (int qq = 0; qq < 4; qq++) Bb[qq] = *(const float4*)(xrow + qq * 4);
        for (int i = 0; i < 32; i++) {
            int i4 = (i + 4 < 32) ? i + 4 : 31;
            int i1 = (i + 1 < 32) ? i + 1 : 31;
            float dtn = dtp[(size_t)i4 * DD];
            float xcn = xcp[(size_t)i4 * DD];
            float4 nB[4];
            const float* nBr = xrow + i1 * 80;
#pragma unroll
            for (int qq = 0; qq < 4; qq++) nB[qq] = *(const float4*)(nBr + qq * 4);

            float dx = dt0 * xc0;
            dtsum += dt0;
            f32x2 dtp2 = (f32x2){ dt0, dt0 };
            f32x2 dx2 = (f32x2){ dx, dx };
#pragma unroll
            for (int k = 0; k < 8; k++) {
                float4 qb = Bb[k >> 1];
                f32x2 bl2 = (k & 1) ? (f32x2){ qb.z, qb.w } : (f32x2){ qb.x, qb.y };
                f32x2 arg = pk_mul(dtp2, Ac2[k]);
                f32x2 e2;
                e2[0] = exp2_fast(arg[0]);
                e2[1] = exp2_fast(arg[1]);
                f32x2 dxb = pk_mul(dx2, bl2);
                S2[k] = pk_fma(e2, S2[k], dxb);
            }
            dt0 = dt1; dt1 = dt2; dt2 = dt3; dt3 = dtn;
            xc0 = xc1; xc1 = xc2; xc2 = xc3; xc3 = xcn;
#pragma unroll
            for (int qq = 0; qq < 4; qq++) Bb[qq] = nB[qq];
        }
    }
    {
        float* pw = &Pl[(c * 8 + dl) * 16];
        float* sw = &Sl[(c * 8 + dl) * 16];
#pragma unroll
        for (int q2 = 0; q2 < 4; q2++) {
            float4 pv = { exp2_fast(Ac2[q2 * 2][0] * dtsum),
                          exp2_fast(Ac2[q2 * 2][1] * dtsum),
                          exp2_fast(Ac2[q2 * 2 + 1][0] * dtsum),
                          exp2_fast(Ac2[q2 * 2 + 1][1] * dtsum) };
            float4 sv = { S2[q2 * 2][0], S2[q2 * 2][1],
                          S2[q2 * 2 + 1][0], S2[q2 * 2 + 1][1] };
            *(float4*)(pw + q2 * 4) = pv;
            *(float4*)(sw + q2 * 4) = sv;
        }
    }
    __syncthreads();
    // ---- Phase 2: serial combine, thread per (d,n); H overwrites Pl
    if (tid < 128) {
        int d2 = tid >> 4, n2 = tid & 15;
        float hh = 0.0f;
#pragma unroll
        for (int cc = 0; cc < 32; cc++) {
            int idx = (cc * 8 + d2) * 16 + n2;
            float Pv = Pl[idx], Sv = Sl[idx];
            Pl[idx] = hh;
            hh = Pv * hh + Sv;
        }
    }
    __syncthreads();
    f32x2 h2[8];
    {
        const float* hr = &Pl[(c * 8 + dl) * 16];
#pragma unroll
        for (int q2 = 0; q2 < 4; q2++) {
            float4 v4 = *(const float4*)(hr + q2 * 4);
            h2[q2 * 2]     = (f32x2){ v4.x, v4.y };
            h2[q2 * 2 + 1] = (f32x2){ v4.z, v4.w };
        }
    }
    float Dv = Dp[d];
    // ---- Phase 3: rescan from h_in, gate, write (4-deep dt/xc/z, 1-deep B/C)
    {
        float dt0 = dtp[0],      xc0 = xcp[0],      zv0 = zp[0];
        float dt1 = dtp[DD],     xc1 = xcp[DD],     zv1 = zp[DD];
        float dt2 = dtp[2 * DD], xc2 = xcp[2 * DD], zv2 = zp[2 * DD];
        float dt3 = dtp[3 * DD], xc3 = xcp[3 * DD], zv3 = zp[3 * DD];
        float4 Bb[4], Cc[4];
#pragma unroll
        for (int qq = 0; qq < 4; qq++) {
            Bb[qq] = *(const float4*)(xrow + qq * 4);
            Cc[qq] = *(const float4*)(xrow + 16 + qq * 4);
        }
        for (int i = 0; i < 32; i++) {
            int i4 = (i + 4 < 32) ? i + 4 : 31;
            int i1 = (i + 1 < 32) ? i + 1 : 31;
            float dtn = dtp[(size_t)i4 * DD];
            float xcn = xcp[(size_t)i4 * DD];
            float zvn = zp[(size_t)i4 * DD];
            float4 nB[4], nC[4];
            const float* nBr = xrow + i1 * 80;
#pragma unroll
            for (int qq = 0; qq < 4; qq++) {
                nB[qq] = *(const float4*)(nBr + qq * 4);
                nC[qq] = *(const float4*)(nBr + 16 + qq * 4);
            }
            float dx = dt0 * xc0;
            f32x2 dtp2 = (f32x2){ dt0, dt0 };
            f32x2 dx2 = (f32x2){ dx, dx };
            f32x2 y2 = (f32x2){ Dv * xc0, 0.0f };
#pragma unroll
            for (int k = 0; k < 8; k++) {
                float4 qb = Bb[k >> 1];
                float4 qc = Cc[k >> 1];
                f32x2 bl2 = (k & 1) ? (f32x2){ qb.z, qb.w } : (f32x2){ qb.x, qb.y };
                f32x2 cl2 = (k & 1) ? (f32x2){ qc.z, qc.w } : (f32x2){ qc.x, qc.y };
                f32x2 arg = pk_mul(dtp2, Ac2[k]);
                f32x2 e2;
                e2[0] = exp2_fast(arg[0]);
                e2[1] = exp2_fast(arg[1]);
                f32x2 dxb = pk_mul(dx2, bl2);
                h2[k] = pk_fma(e2, h2[k], dxb);
                y2 = pk_fma(h2[k], cl2, y2);
            }
            float y = y2[0] + y2[1];
            float gated = y * silu_f(zv0);
            if (YB) ybp[(size_t)i * DD] = f2bf(gated);
            else    zp[(size_t)i * DD] = gated;
            dt0 = dt1; dt1 = dt2; dt2 = dt3; dt3 = dtn;
            xc0 = xc1; xc1 = xc2; xc2 = xc3; xc3 = xcn;
            zv0 = zv1; zv1 = zv2; zv2 = zv3; zv3 = zvn;
#pragma unroll
            for (int qq = 0; qq < 4; qq++) { Bb[qq] = nB[qq]; Cc[qq] = nC[qq]; }
        }
    }
}

// ---------------------------------------------------------------------------
extern "C" void kernel_launch(void* const* d_in, const int* in_sizes, int n_in,
                              void* d_out, int out_size, void* d_ws, size_t ws_size,
                              hipStream_t stream) {
    const float* x      = (const float*)d_in[0];
    // d_in[1] batch_params, d_in[2] has_velocity: provably no effect
    const float* norm_w = (const float*)d_in[3];
    const float* in_w   = (const float*)d_in[4];
    const float* in_b   = (const float*)d_in[5];
    const float* conv_w = (const float*)d_in[6];
    const float* conv_b = (const float*)d_in[7];
    const float* xp_w   = (const float*)d_in[8];
    const float* dt_w   = (const float*)d_in[9];
    const float* dt_b   = (const float*)d_in[10];
    const float* A_log  = (const float*)d_in[11];
    const float* Dp     = (const float*)d_in[12];
    const float* out_w  = (const float*)d_in[13];
    const float* out_b  = (const float*)d_in[14];
    float* out = (float*)d_out;

    const size_t S = (size_t)BB * LL * DD;     // 6291456
    const size_t X = (size_t)BB * LL * 80;     // 655360
    float* res   = (float*)d_ws;               // residual (fp32)
    float* slotA = res + S;                    // hidb (bf16) then xc (fp32)
    float* slotB = slotA + S;                  // xin then dtf (fp32)
    float* zf    = slotB + S;                  // z (b,t,d)
    float* xdbl  = zf + S;                     // (B*L, 80)
    short* inw_b  = (short*)(xdbl + X);                      // 1536x768 bf16
    short* outw_b = inw_b + 1536 * DD;                       // 768x768 bf16
    short* ybf    = outw_b + DD * DD;                        // gated y bf16
    float* xpart  = (float*)(ybf + S);                       // 8 x (B*L,80)

    short* hidb = (short*)slotA;
    float* xc   = slotA;
    float* xin  = slotB;
    float* dtf  = slotB;

    const int M = BB * LL;                     // 8192

    // workspace guards
    size_t needYB = (size_t)((char*)(ybf + S) - (char*)d_ws);
    size_t needXP = (size_t)((char*)(xpart + 8 * X) - (char*)d_ws);
    bool useYB = ws_size >= needYB;
    bool useXP = ws_size >= needXP;

    // 0. weight conversions (one launch)
    {
        int n1 = 1536 * DD / 4, n2 = DD * DD / 4;
        k_cvt2<<<(n1 + n2 + 255) / 256, 256, 0, stream>>>(in_w, inw_b, n1,
                                                          out_w, outw_b, n2);
    }

    // 1. pos + residual + rmsnorm (hidden bf16)
    k_pos_rms<<<M, 256, 0, stream>>>(x, norm_w, res, hidb);

    // 2. in_proj (MFMA, BK=64): -> xin (b,t,d) | zf (b,t,d)
    gemm_in64<<<dim3(1536 / 128, M / 128), 256, 0, stream>>>(
        hidb, inw_b, in_b, xin, zf);

    // 3. depthwise conv + silu: xin -> xc (x4-vectorized)
    k_conv<<<(int)(S / 1024), 256, 0, stream>>>(xin, conv_w, conv_b, xc);

    // 4. x_proj: split-K partials + reduce (no atomics); fallback gemm_nt
    if (useXP) {
        k_xproj<<<dim3(8, M / 64), 256, 0, stream>>>(xc, xp_w, xpart);
        k_xred<<<(int)(X / 4 + 255) / 256, 256, 0, stream>>>(xpart, xdbl);
    } else {
        gemm_nt<0><<<dim3(2, M / 64), 256, 0, stream>>>(
            xc, DD, xp_w, DD, RR + 2 * NNs, DD, nullptr, xdbl, 80);
    }

    // 5. dt_proj + softplus -> dtf (b,t,d) (reuses slotB; xin dead)
    gemm_nt<2><<<dim3(DD / 64, M / 64), 256, 0, stream>>>(
        xdbl, 80, dt_w, RR, DD, RR, dt_b, dtf, DD);

    // 6. scan + gating; 7. out_proj (128x64 tile, 768 blocks balanced)
    if (useYB) {
        k_scan<true><<<768, 256, 0, stream>>>(dtf, xc, xdbl, A_log, Dp, zf, ybf);
        gemm_mfma_n64<false><<<dim3(DD / 64, M / 128), 256, 0, stream>>>(
            ybf, outw_b, DD, out_b, res, out);
    } else {
        k_scan<false><<<768, 256, 0, stream>>>(dtf, xc, xdbl, A_log, Dp, zf, ybf);
        gemm_mfma_n64<true><<<dim3(DD / 64, M / 128), 256, 0, stream>>>(
            zf, outw_b, DD, out_b, res, out);
    }
}